// Round 1
// baseline (1120.651 us; speedup 1.0000x reference)
//
#include <hip/hip_runtime.h>
#include <hip/hip_bf16.h>

#define B_    2
#define N_    4096
#define NV_   32768
#define HID_  128
#define XD_   128
#define YD_   128
#define ZD_   16
#define PLANE (XD_*YD_*ZD_)      // 262144
#define LOCS  (B_*PLANE)         // 524288
#define STEP  (100.0f/15.0f)
#define NT    32                 // n-tile for fuse kernel
#define VB    32                 // v-tile per block

__device__ __forceinline__ float anchor_coord(int i) {
    return fmaf((float)i, STEP, -50.0f);
}

// ---------------- MLP: x = relu(in @ W1 + b1) @ W2 + b2 ----------------
// 2 rows per block of 256 threads (halves W2 re-reads).
__global__ __launch_bounds__(256) void mlp_kernel(
    const float* __restrict__ pos, const float* __restrict__ scl,
    const float* __restrict__ rot, const float* __restrict__ opa,
    const float* __restrict__ W1,  const float* __restrict__ b1,
    const float* __restrict__ W2,  const float* __restrict__ b2,
    float* __restrict__ xw)
{
    int rg = threadIdx.x >> 7;       // 0..1
    int j  = threadIdx.x & 127;
    int r  = blockIdx.x * 2 + rg;    // row in [0, B*N)
    __shared__ float sin_[2][11];
    __shared__ float h[2][HID_];
    if (j < 11) {
        float val;
        if (j < 3)       val = pos[r*3 + j];
        else if (j < 6)  val = scl[r*3 + (j-3)];
        else if (j < 10) val = rot[r*4 + (j-6)];
        else             val = opa[r];
        sin_[rg][j] = val;
    }
    __syncthreads();
    float a = b1[j];
    #pragma unroll
    for (int i = 0; i < 11; ++i) a = fmaf(sin_[rg][i], W1[i*HID_ + j], a);
    h[rg][j] = fmaxf(a, 0.0f);
    __syncthreads();
    float o = b2[j];
    for (int k = 0; k < HID_; ++k) o = fmaf(h[rg][k], W2[k*HID_ + j], o);
    xw[(size_t)r*HID_ + j] = o;
}

// ------------- scatter: winner map (last v wins == max v) + batch buckets -------------
__global__ __launch_bounds__(256) void scatter_kernel(
    const int* __restrict__ vc, int* __restrict__ map,
    int* __restrict__ cnt, int* __restrict__ vlist)
{
    int v = blockIdx.x * 256 + threadIdx.x;
    if (v >= NV_) return;
    int4 c = ((const int4*)vc)[v];
    int loc = ((c.x*XD_ + c.y)*YD_ + c.z)*ZD_ + c.w;
    atomicMax(&map[loc], v);
    int p = atomicAdd(&cnt[c.x], 1);
    vlist[c.x*NV_ + p] = v;
}

// ------------- pass A: per-v softmax max m and inverse denominator -------------
// one wave per v; each lane covers 64 anchors; two passes (max, then sum).
__global__ __launch_bounds__(256) void ml_kernel(
    const int* __restrict__ vc, float* __restrict__ ml)
{
    int v  = blockIdx.x * 4 + (threadIdx.x >> 6);
    int ln = threadIdx.x & 63;
    int4 c = ((const int4*)vc)[v];
    float vx = (float)c.y, vy = (float)c.z, vz = (float)c.w;
    float t1 = vx*vx + vy*vy + vz*vz;

    float m = -3.4e38f;
    for (int k = 0; k < 64; ++k) {
        int n = ln*64 + k;
        int ix = n >> 8, iy = (n >> 4) & 15, iz = n & 15;
        float ax = anchor_coord(ix), ay = anchor_coord(iy), az = anchor_coord(iz);
        float t2  = ax*ax + ay*ay + az*az;
        float dot = vx*ax + vy*ay + vz*az;
        float d2  = fmaxf((t1 + t2) - 2.0f*dot, 0.0f);
        m = fmaxf(m, -sqrtf(d2));
    }
    #pragma unroll
    for (int off = 32; off; off >>= 1) m = fmaxf(m, __shfl_xor(m, off));

    float l = 0.0f;
    for (int k = 0; k < 64; ++k) {
        int n = ln*64 + k;
        int ix = n >> 8, iy = (n >> 4) & 15, iz = n & 15;
        float ax = anchor_coord(ix), ay = anchor_coord(iy), az = anchor_coord(iz);
        float t2  = ax*ax + ay*ay + az*az;
        float dot = vx*ax + vy*ay + vz*az;
        float d2  = fmaxf((t1 + t2) - 2.0f*dot, 0.0f);
        l += __expf(-sqrtf(d2) - m);
    }
    #pragma unroll
    for (int off = 32; off; off >>= 1) l += __shfl_xor(l, off);

    if (ln == 0) { ml[(size_t)v*2] = m; ml[(size_t)v*2 + 1] = 1.0f / l; }
}

// ------------- pass B: fused[v,:] = sum_n p(v,n) * x[b_v,n,:] -------------
// Blocks are batch-uniform via vlist segments. 32 v x 128 d per block,
// 4v x 4d register tile per thread, x tile (32n x 128d) staged in LDS.
__global__ __launch_bounds__(256) void fuse_kernel(
    const float* __restrict__ xw, const float* __restrict__ ml,
    const int* __restrict__ vc,   const int* __restrict__ vlist,
    const int* __restrict__ cnt,  float* __restrict__ fused)
{
    int seg = blockIdx.x >> 10;          // batch
    int bi  = blockIdx.x & 1023;
    int count = cnt[seg];
    int vbase = bi * VB;
    if (vbase >= count) return;
    int nv = min(VB, count - vbase);

    __shared__ float xt[NT][HID_];       // 16 KB
    __shared__ float pt[NT][VB];         // 4 KB
    __shared__ float svx[VB], svy[VB], svz[VB], st1[VB], sm[VB], sil[VB];
    __shared__ int   svid[VB];

    int tid = threadIdx.x;
    if (tid < VB) {
        int j = tid;
        int vid = -1; float fx=0, fy=0, fz=0, mm=0, il=0;
        if (j < nv) {
            vid = vlist[seg*NV_ + vbase + j];
            int4 c = ((const int4*)vc)[vid];
            fx = (float)c.y; fy = (float)c.z; fz = (float)c.w;
            mm = ml[(size_t)vid*2]; il = ml[(size_t)vid*2 + 1];
        }
        svid[j]=vid; svx[j]=fx; svy[j]=fy; svz[j]=fz;
        st1[j]=fx*fx + fy*fy + fz*fz; sm[j]=mm; sil[j]=il;
    }
    __syncthreads();

    // per-thread score assignment: one v, 4 n's per tile
    int sv  = tid & 31;
    int sn0 = (tid >> 5) << 2;
    float pvx = svx[sv], pvy = svy[sv], pvz = svz[sv];
    float pt1 = st1[sv], pm = sm[sv], pil = sil[sv];

    // accumulate assignment: 4v x 4d
    int v0 = (tid & 7) << 2;
    int d0 = (tid >> 3) << 2;
    float acc[4][4];
    #pragma unroll
    for (int a = 0; a < 4; ++a)
        #pragma unroll
        for (int b = 0; b < 4; ++b) acc[a][b] = 0.0f;

    const float* xg = xw + (size_t)seg * N_ * HID_;

    for (int t = 0; t < N_/NT; ++t) {
        int n0 = t * NT;
        __syncthreads();
        // stage x tile: rows n0..n0+31, coalesced float4
        {
            int cc = (tid & 31) << 2;
            int rr0 = tid >> 5;
            #pragma unroll
            for (int rr = 0; rr < 4; ++rr) {
                int n = rr0 + (rr << 3);
                float4 val = *(const float4*)&xg[(size_t)(n0 + n)*HID_ + cc];
                *(float4*)&xt[n][cc] = val;
            }
        }
        // scores for this tile
        #pragma unroll
        for (int nn = 0; nn < 4; ++nn) {
            int n  = sn0 + nn;
            int ng = n0 + n;
            int ix = ng >> 8, iy = (ng >> 4) & 15, iz = ng & 15;
            float ax = anchor_coord(ix), ay = anchor_coord(iy), az = anchor_coord(iz);
            float t2  = ax*ax + ay*ay + az*az;
            float dot = pvx*ax + pvy*ay + pvz*az;
            float d2  = fmaxf((pt1 + t2) - 2.0f*dot, 0.0f);
            float s   = -sqrtf(d2);
            pt[n][sv] = __expf(s - pm) * pil;   // pil==0 for invalid v -> p=0
        }
        __syncthreads();
        // accumulate
        #pragma unroll 4
        for (int n = 0; n < NT; ++n) {
            float4 xv = *(const float4*)&xt[n][d0];
            float4 pv = *(const float4*)&pt[n][v0];
            acc[0][0] = fmaf(pv.x, xv.x, acc[0][0]);
            acc[0][1] = fmaf(pv.x, xv.y, acc[0][1]);
            acc[0][2] = fmaf(pv.x, xv.z, acc[0][2]);
            acc[0][3] = fmaf(pv.x, xv.w, acc[0][3]);
            acc[1][0] = fmaf(pv.y, xv.x, acc[1][0]);
            acc[1][1] = fmaf(pv.y, xv.y, acc[1][1]);
            acc[1][2] = fmaf(pv.y, xv.z, acc[1][2]);
            acc[1][3] = fmaf(pv.y, xv.w, acc[1][3]);
            acc[2][0] = fmaf(pv.z, xv.x, acc[2][0]);
            acc[2][1] = fmaf(pv.z, xv.y, acc[2][1]);
            acc[2][2] = fmaf(pv.z, xv.z, acc[2][2]);
            acc[2][3] = fmaf(pv.z, xv.w, acc[2][3]);
            acc[3][0] = fmaf(pv.w, xv.x, acc[3][0]);
            acc[3][1] = fmaf(pv.w, xv.y, acc[3][1]);
            acc[3][2] = fmaf(pv.w, xv.z, acc[3][2]);
            acc[3][3] = fmaf(pv.w, xv.w, acc[3][3]);
        }
    }

    #pragma unroll
    for (int vv = 0; vv < 4; ++vv) {
        int v = v0 + vv;
        if (v < nv) {
            float4 o = make_float4(acc[vv][0], acc[vv][1], acc[vv][2], acc[vv][3]);
            *(float4*)&fused[(size_t)svid[v]*HID_ + d0] = o;
        }
    }
}

// ------------- output: single full-coverage coalesced write -------------
__global__ __launch_bounds__(256) void out_kernel(
    const int* __restrict__ map, const float* __restrict__ fused,
    float* __restrict__ out)
{
    int loc = blockIdx.x * 256 + threadIdx.x;
    int b   = loc >> 18;                 // PLANE = 2^18
    int rem = loc & (PLANE - 1);
    int v   = map[loc];
    const float* frow = fused + (size_t)(v < 0 ? 0 : v) * HID_;
    size_t obase = ((size_t)b * HID_) * PLANE + rem;
    for (int ch = 0; ch < HID_; ++ch) {
        float val = 0.0f;
        if (v >= 0) val = frow[ch];
        out[obase + (size_t)ch * PLANE] = val;
    }
}

extern "C" void kernel_launch(void* const* d_in, const int* in_sizes, int n_in,
                              void* d_out, int out_size, void* d_ws, size_t ws_size,
                              hipStream_t stream) {
    const float* pos = (const float*)d_in[0];
    const float* scl = (const float*)d_in[1];
    const float* rot = (const float*)d_in[2];
    const float* opa = (const float*)d_in[3];
    const float* W1  = (const float*)d_in[4];
    const float* b1  = (const float*)d_in[5];
    const float* W2  = (const float*)d_in[6];
    const float* b2  = (const float*)d_in[7];
    const int*   vc  = (const int*)d_in[8];
    float* out = (float*)d_out;

    char* ws = (char*)d_ws;
    float* xw    = (float*)(ws);                    // 4 MB: x[B][N][128]
    float* ml    = (float*)(ws + (4u<<20));         // 256 KB: [NV][m, 1/l]
    float* fused = (float*)(ws + (8u<<20));         // 16 MB: fused[NV][128]
    int*   map   = (int*)  (ws + (24u<<20));        // 2 MB: loc -> winner v
    int*   vlist = (int*)  (ws + (26u<<20));        // 256 KB: batch buckets
    int*   cnt   = (int*)  (ws + (27u<<20));        // 8 B

    hipMemsetAsync(map, 0xFF, LOCS*sizeof(int), stream);   // -1
    hipMemsetAsync(cnt, 0, 2*sizeof(int), stream);

    mlp_kernel<<<(B_*N_)/2, 256, 0, stream>>>(pos, scl, rot, opa, W1, b1, W2, b2, xw);
    scatter_kernel<<<NV_/256, 256, 0, stream>>>(vc, map, cnt, vlist);
    ml_kernel<<<NV_/4, 256, 0, stream>>>(vc, ml);
    fuse_kernel<<<2048, 256, 0, stream>>>(xw, ml, vc, vlist, cnt, fused);
    out_kernel<<<LOCS/256, 256, 0, stream>>>(map, fused, out);
}

// Round 2
// 568.477 us; speedup vs baseline: 1.9713x; 1.9713x over previous
//
#include <hip/hip_runtime.h>
#include <hip/hip_bf16.h>

#define B_    2
#define N_    4096
#define NV_   32768
#define HID_  128
#define XD_   128
#define YD_   128
#define ZD_   16
#define PLANE (XD_*YD_*ZD_)      // 262144
#define LOCS  (B_*PLANE)         // 524288
#define STEP  (100.0f/15.0f)
#define NT    64                 // K-tile
#define VB    64                 // v rows per block

typedef __attribute__((ext_vector_type(8))) short short8;
typedef __attribute__((ext_vector_type(4))) float f32x4;

__device__ __forceinline__ float anchor_coord(int i) {
    return fmaf((float)i, STEP, -50.0f);
}
__device__ __forceinline__ unsigned short f2bf(float x) {
    unsigned u = __float_as_uint(x);
    return (unsigned short)((u + 0x7fffu + ((u >> 16) & 1u)) >> 16);
}

// ---------------- MLP: x = relu(in @ W1 + b1) @ W2 + b2 -> xwT bf16 [b][d][n] ----------------
__global__ __launch_bounds__(256) void mlp_kernel(
    const float* __restrict__ pos, const float* __restrict__ scl,
    const float* __restrict__ rot, const float* __restrict__ opa,
    const float* __restrict__ W1,  const float* __restrict__ b1,
    const float* __restrict__ W2,  const float* __restrict__ b2,
    unsigned short* __restrict__ xwT)
{
    int rg = threadIdx.x >> 7;       // 0..1
    int j  = threadIdx.x & 127;
    int r  = blockIdx.x * 2 + rg;    // row in [0, B*N)
    __shared__ float sin_[2][11];
    __shared__ float h[2][HID_];
    if (j < 11) {
        float val;
        if (j < 3)       val = pos[r*3 + j];
        else if (j < 6)  val = scl[r*3 + (j-3)];
        else if (j < 10) val = rot[r*4 + (j-6)];
        else             val = opa[r];
        sin_[rg][j] = val;
    }
    __syncthreads();
    float a = b1[j];
    #pragma unroll
    for (int i = 0; i < 11; ++i) a = fmaf(sin_[rg][i], W1[i*HID_ + j], a);
    h[rg][j] = fmaxf(a, 0.0f);
    __syncthreads();
    float o = b2[j];
    for (int k = 0; k < HID_; ++k) o = fmaf(h[rg][k], W2[k*HID_ + j], o);
    int b = r >> 12, n = r & 4095;
    xwT[((size_t)(b*HID_ + j))*N_ + n] = f2bf(o);
}

// ------------- scatter: winner map (last v wins == max v) + batch buckets -------------
__global__ __launch_bounds__(256) void scatter_kernel(
    const int* __restrict__ vc, int* __restrict__ map,
    int* __restrict__ cnt, int* __restrict__ vlist)
{
    int v = blockIdx.x * 256 + threadIdx.x;
    if (v >= NV_) return;
    int4 c = ((const int4*)vc)[v];
    int loc = ((c.x*XD_ + c.y)*YD_ + c.z)*ZD_ + c.w;
    atomicMax(&map[loc], v);
    int p = atomicAdd(&cnt[c.x], 1);
    vlist[c.x*NV_ + p] = v;
}

// ------------- pass A: per-v (dmin, 1/l) via single online pass, 8 lanes per v -------------
__global__ __launch_bounds__(256) void ml_kernel(
    const int* __restrict__ vc, float2* __restrict__ ml)
{
    int gid = blockIdx.x * 256 + threadIdx.x;
    int v = gid >> 3, sub = gid & 7;
    int4 c = ((const int4*)vc)[v];
    float vx = (float)c.y, vy = (float)c.z, vz = (float)c.w;
    float dz2_[16];
    #pragma unroll 16
    for (int iz = 0; iz < 16; ++iz) { float t = vz - anchor_coord(iz); dz2_[iz] = t*t; }

    float m = 1e30f, l = 0.0f;
    #pragma unroll
    for (int i = 0; i < 2; ++i) {
        float dx = vx - anchor_coord(sub*2 + i);
        float dx2 = dx*dx;
        for (int iy = 0; iy < 16; ++iy) {
            float dy = vy - anchor_coord(iy);
            float bxy = fmaf(dy, dy, dx2);
            #pragma unroll 16
            for (int iz = 0; iz < 16; ++iz) {
                float d = sqrtf(bxy + dz2_[iz]);
                float dm = d - m;
                float e = __expf(-fabsf(dm));
                bool nm = dm < 0.0f;
                l = nm ? fmaf(l, e, 1.0f) : (l + e);
                m = nm ? d : m;
            }
        }
    }
    #pragma unroll
    for (int off = 1; off < 8; off <<= 1) {
        float m2 = __shfl_xor(m, off);
        float l2 = __shfl_xor(l, off);
        float mn = fminf(m, m2);
        l = l * __expf(mn - m) + l2 * __expf(mn - m2);
        m = mn;
    }
    if (sub == 0) ml[v] = make_float2(m, 1.0f / l);
}

// ------------- pass B: fused[v,:] = sum_n p(v,n) * x[b_v,n,:] via bf16 MFMA -------------
// Block: 64 v (batch-uniform) x 128 d. 4 waves in 2x2 (32v x 64d each).
// P tile computed in-register -> swizzled LDS; X^T tile staged bf16 swizzled.
__global__ __launch_bounds__(256) void fuse_kernel(
    const unsigned short* __restrict__ xwT, const float2* __restrict__ ml,
    const int* __restrict__ vc,   const int* __restrict__ vlist,
    const int* __restrict__ cnt,  float* __restrict__ fused)
{
    int seg = blockIdx.x >> 9;
    int bi  = blockIdx.x & 511;
    int count = cnt[seg];
    int vbase = bi * VB;
    if (vbase >= count) return;
    int nv = min(VB, count - vbase);

    __shared__ uint4 sXT[128*8];   // X^T tile: 128 d x 64 k bf16, 16B-block swizzled
    __shared__ uint4 sP [64*8];    // P  tile:  64 v x 64 k bf16, swizzled
    __shared__ float svx[VB], svy[VB], svz[VB], sdm[VB], sil[VB];
    __shared__ int   svid[VB];

    int tid = threadIdx.x;
    if (tid < VB) {
        int vid = -1; float fx=0, fy=0, fz=0, dm=0, il=0;
        if (tid < nv) {
            vid = vlist[seg*NV_ + vbase + tid];
            int4 c = ((const int4*)vc)[vid];
            fx = (float)c.y; fy = (float)c.z; fz = (float)c.w;
            float2 t = ml[vid]; dm = t.x; il = t.y;
        }
        svid[tid]=vid; svx[tid]=fx; svy[tid]=fy; svz[tid]=fz; sdm[tid]=dm; sil[tid]=il;
    }
    __syncthreads();

    // P-compute assignment: v = tid&63, n-chunk = tid>>6 (16 consecutive n)
    int pv = tid & 63, png = tid >> 6;
    float pvx = svx[pv], pvy = svy[pv], pvz = svz[pv];
    float pdm = sdm[pv], pil = sil[pv];
    float dz2_[16];
    #pragma unroll 16
    for (int iz = 0; iz < 16; ++iz) { float t = pvz - anchor_coord(iz); dz2_[iz] = t*t; }

    // wave/fragment ids
    int wv = tid >> 6, L = tid & 63;
    int wr = wv >> 1, wc = wv & 1;       // 2x2: wr = v-half, wc = d-half
    int r  = L & 15,  g  = L >> 4;
    f32x4 acc[2][4];
    #pragma unroll
    for (int i = 0; i < 2; ++i)
        #pragma unroll
        for (int jj = 0; jj < 4; ++jj) acc[i][jj] = (f32x4){0.f,0.f,0.f,0.f};

    // staging assignment: d-row = tid>>1, half = tid&1 (32 bf16 = 4x16B each)
    int sd = tid >> 1, ss = tid & 1;
    const uint4* xg = (const uint4*)xwT + ((size_t)(seg*128 + sd) * N_ >> 3);

    for (int t = 0; t < N_/NT; ++t) {
        int n0 = t * NT;
        __syncthreads();
        // ---- stage X^T tile (global -> swizzled LDS) ----
        {
            const uint4* src = xg + (n0 >> 3) + ss*4;
            int dbase = sd * 8;
            #pragma unroll
            for (int i = 0; i < 4; ++i) {
                int blk = ss*4 + i;
                sXT[dbase + (blk ^ (sd & 7))] = src[i];
            }
        }
        // ---- compute P chunk: 16 n at nc = n0 + png*16 ----
        {
            int nc = n0 + png*16;
            int idx = nc >> 4;
            float ax = anchor_coord(idx >> 4);
            float ay = anchor_coord(idx & 15);
            float dxv = pvx - ax, dyv = pvy - ay;
            float bxy = fmaf(dxv, dxv, dyv*dyv);
            unsigned u[8];
            #pragma unroll
            for (int jj = 0; jj < 8; ++jj) {
                float d0 = sqrtf(bxy + dz2_[2*jj]);
                float d1 = sqrtf(bxy + dz2_[2*jj+1]);
                float p0 = __expf(pdm - d0) * pil;
                float p1 = __expf(pdm - d1) * pil;
                asm("v_cvt_pk_bf16_f32 %0, %1, %2" : "=v"(u[jj]) : "v"(p0), "v"(p1));
            }
            int pb = pv * 8;
            sP[pb + ((png*2    ) ^ (pv & 7))] = make_uint4(u[0],u[1],u[2],u[3]);
            sP[pb + ((png*2 + 1) ^ (pv & 7))] = make_uint4(u[4],u[5],u[6],u[7]);
        }
        __syncthreads();
        // ---- MFMA ----
        #pragma unroll
        for (int ks = 0; ks < 2; ++ks) {
            int blk = ks*4 + g;
            int va0 = wr*32 + r;
            int va1 = va0 + 16;
            short8 a0 = *(const short8*)&sP[va0*8 + (blk ^ (va0 & 7))];
            short8 a1 = *(const short8*)&sP[va1*8 + (blk ^ (va1 & 7))];
            #pragma unroll
            for (int df = 0; df < 4; ++df) {
                int dr = wc*64 + df*16 + r;
                short8 bb = *(const short8*)&sXT[dr*8 + (blk ^ (dr & 7))];
                acc[0][df] = __builtin_amdgcn_mfma_f32_16x16x32_bf16(a0, bb, acc[0][df], 0, 0, 0);
                acc[1][df] = __builtin_amdgcn_mfma_f32_16x16x32_bf16(a1, bb, acc[1][df], 0, 0, 0);
            }
        }
    }

    // ---- store: C layout col=lane&15, row=(lane>>4)*4+q ----
    #pragma unroll
    for (int vi = 0; vi < 2; ++vi)
        #pragma unroll
        for (int df = 0; df < 4; ++df)
            #pragma unroll
            for (int q = 0; q < 4; ++q) {
                int vloc = wr*32 + vi*16 + g*4 + q;
                int dcol = wc*64 + df*16 + r;
                if (vloc < nv) {
                    fused[(size_t)svid[vloc]*HID_ + dcol] = acc[vi][df][q];
                }
            }
}

// ------------- output: single full-coverage coalesced write -------------
__global__ __launch_bounds__(256) void out_kernel(
    const int* __restrict__ map, const float* __restrict__ fused,
    float* __restrict__ out)
{
    int loc = blockIdx.x * 256 + threadIdx.x;
    int b   = loc >> 18;
    int rem = loc & (PLANE - 1);
    int v   = map[loc];
    const float* frow = fused + (size_t)(v < 0 ? 0 : v) * HID_;
    size_t obase = ((size_t)b * HID_) * PLANE + rem;
    for (int ch = 0; ch < HID_; ++ch) {
        float val = 0.0f;
        if (v >= 0) val = frow[ch];
        out[obase + (size_t)ch * PLANE] = val;
    }
}

extern "C" void kernel_launch(void* const* d_in, const int* in_sizes, int n_in,
                              void* d_out, int out_size, void* d_ws, size_t ws_size,
                              hipStream_t stream) {
    const float* pos = (const float*)d_in[0];
    const float* scl = (const float*)d_in[1];
    const float* rot = (const float*)d_in[2];
    const float* opa = (const float*)d_in[3];
    const float* W1  = (const float*)d_in[4];
    const float* b1  = (const float*)d_in[5];
    const float* W2  = (const float*)d_in[6];
    const float* b2  = (const float*)d_in[7];
    const int*   vc  = (const int*)d_in[8];
    float* out = (float*)d_out;

    char* ws = (char*)d_ws;
    unsigned short* xwT = (unsigned short*)(ws);        // 2 MB: bf16 x^T [b][128][4096]
    float2* ml    = (float2*)(ws + (2u<<20));           // 256 KB
    float*  fused = (float*) (ws + (4u<<20));           // 16 MB
    int*    map   = (int*)   (ws + (20u<<20));          // 2 MB
    int*    vlist = (int*)   (ws + (22u<<20));          // 256 KB
    int*    cnt   = (int*)   (ws + (23u<<20));          // 8 B

    hipMemsetAsync(map, 0xFF, LOCS*sizeof(int), stream);
    hipMemsetAsync(cnt, 0, 2*sizeof(int), stream);

    mlp_kernel<<<(B_*N_)/2, 256, 0, stream>>>(pos, scl, rot, opa, W1, b1, W2, b2, xwT);
    scatter_kernel<<<NV_/256, 256, 0, stream>>>(vc, map, cnt, vlist);
    ml_kernel<<<(NV_*8)/256, 256, 0, stream>>>(vc, ml);
    fuse_kernel<<<2*512, 256, 0, stream>>>(xwT, ml, vc, vlist, cnt, fused);
    out_kernel<<<LOCS/256, 256, 0, stream>>>(map, fused, out);
}

// Round 3
// 319.555 us; speedup vs baseline: 3.5069x; 1.7790x over previous
//
#include <hip/hip_runtime.h>
#include <hip/hip_bf16.h>

#define B_    2
#define N_    4096
#define NV_   32768
#define HID_  128
#define XD_   128
#define YD_   128
#define ZD_   16
#define PLANE (XD_*YD_*ZD_)      // 262144
#define LOCS  (B_*PLANE)         // 524288
#define STEP  (100.0f/15.0f)
#define NT    64                 // K-tile
#define VB    64                 // v rows per block

typedef __attribute__((ext_vector_type(8))) short short8;
typedef __attribute__((ext_vector_type(4))) float f32x4;

__device__ __forceinline__ float anchor_coord(int i) {
    return fmaf((float)i, STEP, -50.0f);
}
__device__ __forceinline__ unsigned short f2bf(float x) {
    unsigned u = __float_as_uint(x);
    return (unsigned short)((u + 0x7fffu + ((u >> 16) & 1u)) >> 16);
}

// ---------------- MLP: x = relu(in @ W1 + b1) @ W2 + b2 -> xwT bf16 [b][d][n] ----------------
__global__ __launch_bounds__(256) void mlp_kernel(
    const float* __restrict__ pos, const float* __restrict__ scl,
    const float* __restrict__ rot, const float* __restrict__ opa,
    const float* __restrict__ W1,  const float* __restrict__ b1,
    const float* __restrict__ W2,  const float* __restrict__ b2,
    unsigned short* __restrict__ xwT)
{
    int rg = threadIdx.x >> 7;       // 0..1
    int j  = threadIdx.x & 127;
    int r  = blockIdx.x * 2 + rg;    // row in [0, B*N)
    __shared__ float sin_[2][11];
    __shared__ float h[2][HID_];
    if (j < 11) {
        float val;
        if (j < 3)       val = pos[r*3 + j];
        else if (j < 6)  val = scl[r*3 + (j-3)];
        else if (j < 10) val = rot[r*4 + (j-6)];
        else             val = opa[r];
        sin_[rg][j] = val;
    }
    __syncthreads();
    float a = b1[j];
    #pragma unroll
    for (int i = 0; i < 11; ++i) a = fmaf(sin_[rg][i], W1[i*HID_ + j], a);
    h[rg][j] = fmaxf(a, 0.0f);
    __syncthreads();
    float o = b2[j];
    for (int k = 0; k < HID_; ++k) o = fmaf(h[rg][k], W2[k*HID_ + j], o);
    int b = r >> 12, n = r & 4095;
    xwT[((size_t)(b*HID_ + j))*N_ + n] = f2bf(o);
}

// ------------- scatter: winner map + wave-aggregated batch buckets -------------
__global__ __launch_bounds__(256) void scatter_kernel(
    const int* __restrict__ vc, int* __restrict__ map,
    int* __restrict__ cnt, int* __restrict__ vlist)
{
    int v = blockIdx.x * 256 + threadIdx.x;
    int4 c = ((const int4*)vc)[v];
    int loc = ((c.x*XD_ + c.y)*YD_ + c.z)*ZD_ + c.w;
    atomicMax(&map[loc], v);
    // wave-aggregated append: 1 atomic per (wave, batch) instead of per thread
    int lane = threadIdx.x & 63;
    unsigned long long m1 = __ballot(c.x != 0);
    unsigned long long mymask = c.x ? m1 : ~m1;
    int leader = (int)__ffsll(mymask) - 1;
    int total  = __popcll(mymask);
    int rank   = __popcll(mymask & ((1ull << lane) - 1ull));
    int base = 0;
    if (lane == leader) base = atomicAdd(&cnt[c.x], total);
    base = __shfl(base, leader);
    vlist[c.x*NV_ + base + rank] = v;
}

// ------------- pass A: per-v (dmin, 1/l) via single online pass, 8 lanes per v -------------
__global__ __launch_bounds__(256) void ml_kernel(
    const int* __restrict__ vc, float2* __restrict__ ml)
{
    int gid = blockIdx.x * 256 + threadIdx.x;
    int v = gid >> 3, sub = gid & 7;
    int4 c = ((const int4*)vc)[v];
    float vx = (float)c.y, vy = (float)c.z, vz = (float)c.w;
    float dz2_[16];
    #pragma unroll 16
    for (int iz = 0; iz < 16; ++iz) { float t = vz - anchor_coord(iz); dz2_[iz] = t*t; }

    float m = 1e30f, l = 0.0f;
    #pragma unroll
    for (int i = 0; i < 2; ++i) {
        float dx = vx - anchor_coord(sub*2 + i);
        float dx2 = dx*dx;
        for (int iy = 0; iy < 16; ++iy) {
            float dy = vy - anchor_coord(iy);
            float bxy = fmaf(dy, dy, dx2);
            #pragma unroll 16
            for (int iz = 0; iz < 16; ++iz) {
                float d = sqrtf(bxy + dz2_[iz]);
                float dm = d - m;
                float e = __expf(-fabsf(dm));
                bool nm = dm < 0.0f;
                l = nm ? fmaf(l, e, 1.0f) : (l + e);
                m = nm ? d : m;
            }
        }
    }
    #pragma unroll
    for (int off = 1; off < 8; off <<= 1) {
        float m2 = __shfl_xor(m, off);
        float l2 = __shfl_xor(l, off);
        float mn = fminf(m, m2);
        l = l * __expf(mn - m) + l2 * __expf(mn - m2);
        m = mn;
    }
    if (sub == 0) ml[v] = make_float2(m, 1.0f / l);
}

// ------------- pass B: fused[v,:] = sum_n p(v,n) * x[b_v,n,:] via bf16 MFMA -------------
__global__ __launch_bounds__(256) void fuse_kernel(
    const unsigned short* __restrict__ xwT, const float2* __restrict__ ml,
    const int* __restrict__ vc,   const int* __restrict__ vlist,
    const int* __restrict__ cnt,  float* __restrict__ fused)
{
    int seg = blockIdx.x >> 9;
    int bi  = blockIdx.x & 511;
    int count = cnt[seg];
    int vbase = bi * VB;
    if (vbase >= count) return;
    int nv = min(VB, count - vbase);

    __shared__ uint4 sXT[128*8];   // X^T tile: 128 d x 64 k bf16, 16B-block swizzled
    __shared__ uint4 sP [64*8];    // P  tile:  64 v x 64 k bf16, swizzled
    __shared__ float svx[VB], svy[VB], svz[VB], sdm[VB], sil[VB];
    __shared__ int   svid[VB];

    int tid = threadIdx.x;
    if (tid < VB) {
        int vid = -1; float fx=0, fy=0, fz=0, dm=0, il=0;
        if (tid < nv) {
            vid = vlist[seg*NV_ + vbase + tid];
            int4 c = ((const int4*)vc)[vid];
            fx = (float)c.y; fy = (float)c.z; fz = (float)c.w;
            float2 t = ml[vid]; dm = t.x; il = t.y;
        }
        svid[tid]=vid; svx[tid]=fx; svy[tid]=fy; svz[tid]=fz; sdm[tid]=dm; sil[tid]=il;
    }
    __syncthreads();

    // P-compute assignment: v = tid&63, n-chunk = tid>>6 (16 consecutive n)
    int pv = tid & 63, png = tid >> 6;
    float pvx = svx[pv], pvy = svy[pv], pvz = svz[pv];
    float pdm = sdm[pv], pil = sil[pv];
    float dz2_[16];
    #pragma unroll 16
    for (int iz = 0; iz < 16; ++iz) { float t = pvz - anchor_coord(iz); dz2_[iz] = t*t; }

    // wave/fragment ids
    int wv = tid >> 6, L = tid & 63;
    int wr = wv >> 1, wc = wv & 1;       // 2x2: wr = v-half, wc = d-half
    int r  = L & 15,  g  = L >> 4;
    f32x4 acc[2][4];
    #pragma unroll
    for (int i = 0; i < 2; ++i)
        #pragma unroll
        for (int jj = 0; jj < 4; ++jj) acc[i][jj] = (f32x4){0.f,0.f,0.f,0.f};

    // staging assignment: d-row = tid>>1, half = tid&1 (32 bf16 = 4x16B each)
    int sd = tid >> 1, ss = tid & 1;
    const uint4* xg = (const uint4*)xwT + ((size_t)(seg*128 + sd) * N_ >> 3);

    for (int t = 0; t < N_/NT; ++t) {
        int n0 = t * NT;
        __syncthreads();
        // ---- stage X^T tile (global -> swizzled LDS) ----
        {
            const uint4* src = xg + (n0 >> 3) + ss*4;
            int dbase = sd * 8;
            #pragma unroll
            for (int i = 0; i < 4; ++i) {
                int blk = ss*4 + i;
                sXT[dbase + (blk ^ (sd & 7))] = src[i];
            }
        }
        // ---- compute P chunk: 16 n at nc = n0 + png*16 ----
        {
            int nc = n0 + png*16;
            int idx = nc >> 4;
            float ax = anchor_coord(idx >> 4);
            float ay = anchor_coord(idx & 15);
            float dxv = pvx - ax, dyv = pvy - ay;
            float bxy = fmaf(dxv, dxv, dyv*dyv);
            unsigned u[8];
            #pragma unroll
            for (int jj = 0; jj < 8; ++jj) {
                float d0 = sqrtf(bxy + dz2_[2*jj]);
                float d1 = sqrtf(bxy + dz2_[2*jj+1]);
                float p0 = __expf(pdm - d0) * pil;
                float p1 = __expf(pdm - d1) * pil;
                asm("v_cvt_pk_bf16_f32 %0, %1, %2" : "=v"(u[jj]) : "v"(p0), "v"(p1));
            }
            int pb = pv * 8;
            sP[pb + ((png*2    ) ^ (pv & 7))] = make_uint4(u[0],u[1],u[2],u[3]);
            sP[pb + ((png*2 + 1) ^ (pv & 7))] = make_uint4(u[4],u[5],u[6],u[7]);
        }
        __syncthreads();
        // ---- MFMA ----
        #pragma unroll
        for (int ks = 0; ks < 2; ++ks) {
            int blk = ks*4 + g;
            int va0 = wr*32 + r;
            int va1 = va0 + 16;
            short8 a0 = *(const short8*)&sP[va0*8 + (blk ^ (va0 & 7))];
            short8 a1 = *(const short8*)&sP[va1*8 + (blk ^ (va1 & 7))];
            #pragma unroll
            for (int df = 0; df < 4; ++df) {
                int dr = wc*64 + df*16 + r;
                short8 bb = *(const short8*)&sXT[dr*8 + (blk ^ (dr & 7))];
                acc[0][df] = __builtin_amdgcn_mfma_f32_16x16x32_bf16(a0, bb, acc[0][df], 0, 0, 0);
                acc[1][df] = __builtin_amdgcn_mfma_f32_16x16x32_bf16(a1, bb, acc[1][df], 0, 0, 0);
            }
        }
    }

    // ---- store: C layout col=lane&15, row=(lane>>4)*4+q ----
    #pragma unroll
    for (int vi = 0; vi < 2; ++vi)
        #pragma unroll
        for (int df = 0; df < 4; ++df)
            #pragma unroll
            for (int q = 0; q < 4; ++q) {
                int vloc = wr*32 + vi*16 + g*4 + q;
                int dcol = wc*64 + df*16 + r;
                if (vloc < nv) {
                    fused[(size_t)svid[vloc]*HID_ + dcol] = acc[vi][df][q];
                }
            }
}

// ------------- output: single full-coverage coalesced write -------------
__global__ __launch_bounds__(256) void out_kernel(
    const int* __restrict__ map, const float* __restrict__ fused,
    float* __restrict__ out)
{
    int loc = blockIdx.x * 256 + threadIdx.x;
    int b   = loc >> 18;
    int rem = loc & (PLANE - 1);
    int v   = map[loc];
    const float* frow = fused + (size_t)(v < 0 ? 0 : v) * HID_;
    size_t obase = ((size_t)b * HID_) * PLANE + rem;
    for (int ch = 0; ch < HID_; ++ch) {
        float val = 0.0f;
        if (v >= 0) val = frow[ch];
        out[obase + (size_t)ch * PLANE] = val;
    }
}

extern "C" void kernel_launch(void* const* d_in, const int* in_sizes, int n_in,
                              void* d_out, int out_size, void* d_ws, size_t ws_size,
                              hipStream_t stream) {
    const float* pos = (const float*)d_in[0];
    const float* scl = (const float*)d_in[1];
    const float* rot = (const float*)d_in[2];
    const float* opa = (const float*)d_in[3];
    const float* W1  = (const float*)d_in[4];
    const float* b1  = (const float*)d_in[5];
    const float* W2  = (const float*)d_in[6];
    const float* b2  = (const float*)d_in[7];
    const int*   vc  = (const int*)d_in[8];
    float* out = (float*)d_out;

    char* ws = (char*)d_ws;
    unsigned short* xwT = (unsigned short*)(ws);        // 2 MB: bf16 x^T [b][128][4096]
    float2* ml    = (float2*)(ws + (2u<<20));           // 256 KB
    float*  fused = (float*) (ws + (4u<<20));           // 16 MB
    int*    map   = (int*)   (ws + (20u<<20));          // 2 MB
    int*    vlist = (int*)   (ws + (22u<<20));          // 256 KB
    int*    cnt   = (int*)   (ws + (23u<<20));          // 8 B

    hipMemsetAsync(map, 0xFF, LOCS*sizeof(int), stream);
    hipMemsetAsync(cnt, 0, 2*sizeof(int), stream);

    mlp_kernel<<<(B_*N_)/2, 256, 0, stream>>>(pos, scl, rot, opa, W1, b1, W2, b2, xwT);
    scatter_kernel<<<NV_/256, 256, 0, stream>>>(vc, map, cnt, vlist);
    ml_kernel<<<(NV_*8)/256, 256, 0, stream>>>(vc, ml);
    fuse_kernel<<<2*512, 256, 0, stream>>>(xwT, ml, vc, vlist, cnt, fused);
    out_kernel<<<LOCS/256, 256, 0, stream>>>(map, fused, out);
}

// Round 4
// 283.223 us; speedup vs baseline: 3.9568x; 1.1283x over previous
//
#include <hip/hip_runtime.h>
#include <hip/hip_bf16.h>

#define B_    2
#define N_    4096
#define NV_   32768
#define HID_  128
#define XD_   128
#define YD_   128
#define ZD_   16
#define PLANE (XD_*YD_*ZD_)      // 262144
#define LOCS  (B_*PLANE)         // 524288
#define STEP  (100.0f/15.0f)
#define NT    64                 // K-tile
#define VB    64                 // v rows per block
#define KS    4                  // K-split factor
#define L2E   1.4426950408889634f

typedef __attribute__((ext_vector_type(8))) short short8;
typedef __attribute__((ext_vector_type(4))) float f32x4;

__device__ __forceinline__ float anchor_coord(int i) {
    return fmaf((float)i, STEP, -50.0f);
}
// log2e-scaled anchor coordinate: distances in these coords are d*log2e,
// so softmax exp() becomes a bare v_exp_f32 (2^x).
__device__ __forceinline__ float anchor_s(int i) {
    return fmaf((float)i, STEP * L2E, -50.0f * L2E);
}
__device__ __forceinline__ float fexp2(float x) {
    float r; asm("v_exp_f32 %0, %1" : "=v"(r) : "v"(x)); return r;
}
__device__ __forceinline__ unsigned short f2bf(float x) {
    unsigned u = __float_as_uint(x);
    return (unsigned short)((u + 0x7fffu + ((u >> 16) & 1u)) >> 16);
}

// ---------------- MLP: x = relu(in @ W1 + b1) @ W2 + b2 -> xwT bf16 [b][d][n] ----------------
__global__ __launch_bounds__(256) void mlp_kernel(
    const float* __restrict__ pos, const float* __restrict__ scl,
    const float* __restrict__ rot, const float* __restrict__ opa,
    const float* __restrict__ W1,  const float* __restrict__ b1,
    const float* __restrict__ W2,  const float* __restrict__ b2,
    unsigned short* __restrict__ xwT)
{
    int rg = threadIdx.x >> 7;       // 0..1
    int j  = threadIdx.x & 127;
    int r  = blockIdx.x * 2 + rg;    // row in [0, B*N)
    __shared__ float sin_[2][11];
    __shared__ float h[2][HID_];
    if (j < 11) {
        float val;
        if (j < 3)       val = pos[r*3 + j];
        else if (j < 6)  val = scl[r*3 + (j-3)];
        else if (j < 10) val = rot[r*4 + (j-6)];
        else             val = opa[r];
        sin_[rg][j] = val;
    }
    __syncthreads();
    float a = b1[j];
    #pragma unroll
    for (int i = 0; i < 11; ++i) a = fmaf(sin_[rg][i], W1[i*HID_ + j], a);
    h[rg][j] = fmaxf(a, 0.0f);
    __syncthreads();
    float o = b2[j];
    for (int k = 0; k < HID_; ++k) o = fmaf(h[rg][k], W2[k*HID_ + j], o);
    int b = r >> 12, n = r & 4095;
    xwT[((size_t)(b*HID_ + j))*N_ + n] = f2bf(o);
}

// ------------- scatter: winner map + wave-aggregated batch buckets -------------
__global__ __launch_bounds__(256) void scatter_kernel(
    const int* __restrict__ vc, int* __restrict__ map,
    int* __restrict__ cnt, int* __restrict__ vlist)
{
    int v = blockIdx.x * 256 + threadIdx.x;
    int4 c = ((const int4*)vc)[v];
    int loc = ((c.x*XD_ + c.y)*YD_ + c.z)*ZD_ + c.w;
    atomicMax(&map[loc], v);
    int lane = threadIdx.x & 63;
    unsigned long long m1 = __ballot(c.x != 0);
    unsigned long long mymask = c.x ? m1 : ~m1;
    int leader = (int)__ffsll(mymask) - 1;
    int total  = __popcll(mymask);
    int rank   = __popcll(mymask & ((1ull << lane) - 1ull));
    int base = 0;
    if (lane == leader) base = atomicAdd(&cnt[c.x], total);
    base = __shfl(base, leader);
    vlist[c.x*NV_ + base + rank] = v;
}

// ------------- pass A: per-v (m_l2e, 1/l) single online pass, 8 lanes per v -------------
// All coords pre-scaled by log2e so exp() is a bare v_exp_f32.
__global__ __launch_bounds__(256) void ml_kernel(
    const int* __restrict__ vc, float2* __restrict__ ml)
{
    int gid = blockIdx.x * 256 + threadIdx.x;
    int v = gid >> 3, sub = gid & 7;
    int4 c = ((const int4*)vc)[v];
    float vx = (float)c.y * L2E, vy = (float)c.z * L2E, vz = (float)c.w * L2E;
    float dz2_[16];
    #pragma unroll 16
    for (int iz = 0; iz < 16; ++iz) { float t = vz - anchor_s(iz); dz2_[iz] = t*t; }

    float m = 1e30f, l = 0.0f;
    #pragma unroll
    for (int i = 0; i < 2; ++i) {
        float dx = vx - anchor_s(sub*2 + i);
        float dx2 = dx*dx;
        for (int iy = 0; iy < 16; ++iy) {
            float dy = vy - anchor_s(iy);
            float bxy = fmaf(dy, dy, dx2);
            #pragma unroll 16
            for (int iz = 0; iz < 16; ++iz) {
                float d = sqrtf(bxy + dz2_[iz]);
                float dm = d - m;
                float e = fexp2(-fabsf(dm));
                bool nm = dm < 0.0f;
                l = nm ? fmaf(l, e, 1.0f) : (l + e);
                m = nm ? d : m;
            }
        }
    }
    #pragma unroll
    for (int off = 1; off < 8; off <<= 1) {
        float m2 = __shfl_xor(m, off);
        float l2 = __shfl_xor(l, off);
        float mn = fminf(m, m2);
        l = l * fexp2(mn - m) + l2 * fexp2(mn - m2);
        m = mn;
    }
    if (sub == 0) ml[v] = make_float2(m, 1.0f / l);
}

// ------------- pass B: fused[v,:] += sum_{n in kseg} p(v,n) * x[b_v,n,:] via bf16 MFMA -------------
// Grid: [seg][vblock][kseg]. Each block handles 64 v x 128 d x 1024 k; partial
// sums combined with f32 atomicAdd (fused pre-zeroed). 1/l applied at epilogue.
__global__ __launch_bounds__(256) void fuse_kernel(
    const unsigned short* __restrict__ xwT, const float2* __restrict__ ml,
    const int* __restrict__ vc,   const int* __restrict__ vlist,
    const int* __restrict__ cnt,  float* __restrict__ fused)
{
    int bid = blockIdx.x;
    int ks_ = bid & (KS-1);
    int rest = bid >> 2;
    int seg = rest >> 9;
    int bi  = rest & 511;
    int count = cnt[seg];
    int vbase = bi * VB;
    if (vbase >= count) return;
    int nv = min(VB, count - vbase);
    int k0 = ks_ * (N_/KS);

    __shared__ uint4 sXT[128*8];   // X^T tile: 128 d x 64 k bf16, 16B-block swizzled
    __shared__ uint4 sP [64*8];    // P  tile:  64 v x 64 k bf16, swizzled
    __shared__ float svx[VB], svy[VB], svz[VB], sdm[VB], sil[VB];
    __shared__ int   svid[VB];

    int tid = threadIdx.x;
    if (tid < VB) {
        int vid = -1; float fx=0, fy=0, fz=0, dm=0, il=0;
        if (tid < nv) {
            vid = vlist[seg*NV_ + vbase + tid];
            int4 c = ((const int4*)vc)[vid];
            fx = (float)c.y * L2E; fy = (float)c.z * L2E; fz = (float)c.w * L2E;
            float2 t = ml[vid]; dm = t.x; il = t.y;
        }
        svid[tid]=vid; svx[tid]=fx; svy[tid]=fy; svz[tid]=fz; sdm[tid]=dm; sil[tid]=il;
    }
    __syncthreads();

    // P-compute assignment: v = tid&63, n-chunk = tid>>6 (16 consecutive n)
    int pv = tid & 63, png = tid >> 6;
    float pvx = svx[pv], pvy = svy[pv], pvz = svz[pv];
    float pml = sdm[pv];
    float dz2_[16];
    #pragma unroll 16
    for (int iz = 0; iz < 16; ++iz) { float t = pvz - anchor_s(iz); dz2_[iz] = t*t; }

    // wave/fragment ids
    int wv = tid >> 6, L = tid & 63;
    int wr = wv >> 1, wc = wv & 1;       // 2x2: wr = v-half, wc = d-half
    int r  = L & 15,  g  = L >> 4;
    f32x4 acc[2][4];
    #pragma unroll
    for (int i = 0; i < 2; ++i)
        #pragma unroll
        for (int jj = 0; jj < 4; ++jj) acc[i][jj] = (f32x4){0.f,0.f,0.f,0.f};

    // staging assignment: d-row = tid>>1, half = tid&1 (32 bf16 = 4x16B each)
    int sd = tid >> 1, ss = tid & 1;
    const uint4* xg = (const uint4*)xwT + ((size_t)(seg*128 + sd) * N_ >> 3);

    for (int t = 0; t < (N_/KS)/NT; ++t) {
        int n0 = k0 + t * NT;
        __syncthreads();
        // ---- stage X^T tile (global -> swizzled LDS) ----
        {
            const uint4* src = xg + (n0 >> 3) + ss*4;
            int dbase = sd * 8;
            #pragma unroll
            for (int i = 0; i < 4; ++i) {
                int blk = ss*4 + i;
                sXT[dbase + (blk ^ (sd & 7))] = src[i];
            }
        }
        // ---- compute P chunk: 16 n at nc = n0 + png*16 ----
        {
            int nc = n0 + png*16;
            int idx = nc >> 4;
            float ax = anchor_s(idx >> 4);
            float ay = anchor_s(idx & 15);
            float dxv = pvx - ax, dyv = pvy - ay;
            float bxy = fmaf(dxv, dxv, dyv*dyv);
            unsigned u[8];
            #pragma unroll
            for (int jj = 0; jj < 8; ++jj) {
                float d0 = sqrtf(bxy + dz2_[2*jj]);
                float d1 = sqrtf(bxy + dz2_[2*jj+1]);
                float p0 = fexp2(pml - d0);
                float p1 = fexp2(pml - d1);
                asm("v_cvt_pk_bf16_f32 %0, %1, %2" : "=v"(u[jj]) : "v"(p0), "v"(p1));
            }
            int pb = pv * 8;
            sP[pb + ((png*2    ) ^ (pv & 7))] = make_uint4(u[0],u[1],u[2],u[3]);
            sP[pb + ((png*2 + 1) ^ (pv & 7))] = make_uint4(u[4],u[5],u[6],u[7]);
        }
        __syncthreads();
        // ---- MFMA ----
        #pragma unroll
        for (int kss = 0; kss < 2; ++kss) {
            int blk = kss*4 + g;
            int va0 = wr*32 + r;
            int va1 = va0 + 16;
            short8 a0 = *(const short8*)&sP[va0*8 + (blk ^ (va0 & 7))];
            short8 a1 = *(const short8*)&sP[va1*8 + (blk ^ (va1 & 7))];
            #pragma unroll
            for (int df = 0; df < 4; ++df) {
                int dr = wc*64 + df*16 + r;
                short8 bb = *(const short8*)&sXT[dr*8 + (blk ^ (dr & 7))];
                acc[0][df] = __builtin_amdgcn_mfma_f32_16x16x32_bf16(a0, bb, acc[0][df], 0, 0, 0);
                acc[1][df] = __builtin_amdgcn_mfma_f32_16x16x32_bf16(a1, bb, acc[1][df], 0, 0, 0);
            }
        }
    }

    // ---- epilogue: scale by 1/l and accumulate partial into fused ----
    #pragma unroll
    for (int vi = 0; vi < 2; ++vi)
        #pragma unroll
        for (int df = 0; df < 4; ++df)
            #pragma unroll
            for (int q = 0; q < 4; ++q) {
                int vloc = wr*32 + vi*16 + g*4 + q;
                int dcol = wc*64 + df*16 + r;
                if (vloc < nv) {
                    atomicAdd(&fused[(size_t)svid[vloc]*HID_ + dcol],
                              acc[vi][df][q] * sil[vloc]);
                }
            }
}

// ------------- output: full-coverage coalesced write, 4 locs/thread, float4 ops -------------
__global__ __launch_bounds__(256) void out_kernel(
    const int* __restrict__ map, const float* __restrict__ fused,
    float* __restrict__ out)
{
    int q = blockIdx.x * 256 + threadIdx.x;     // quad id, LOCS/4
    int loc0 = q << 2;
    int b   = loc0 >> 18;
    int rem = loc0 & (PLANE - 1);
    int4 vv = ((const int4*)map)[q];
    const float4* r0 = (const float4*)(fused + (size_t)(vv.x < 0 ? 0 : vv.x) * HID_);
    const float4* r1 = (const float4*)(fused + (size_t)(vv.y < 0 ? 0 : vv.y) * HID_);
    const float4* r2 = (const float4*)(fused + (size_t)(vv.z < 0 ? 0 : vv.z) * HID_);
    const float4* r3 = (const float4*)(fused + (size_t)(vv.w < 0 ? 0 : vv.w) * HID_);
    size_t obase = ((size_t)b * HID_) * PLANE + rem;
    const float4 z4 = make_float4(0.f, 0.f, 0.f, 0.f);
    #pragma unroll 4
    for (int chb = 0; chb < 32; ++chb) {
        float4 a = (vv.x >= 0) ? r0[chb] : z4;
        float4 c = (vv.y >= 0) ? r1[chb] : z4;
        float4 d = (vv.z >= 0) ? r2[chb] : z4;
        float4 e = (vv.w >= 0) ? r3[chb] : z4;
        *(float4*)&out[obase + (size_t)(chb*4 + 0) * PLANE] = make_float4(a.x, c.x, d.x, e.x);
        *(float4*)&out[obase + (size_t)(chb*4 + 1) * PLANE] = make_float4(a.y, c.y, d.y, e.y);
        *(float4*)&out[obase + (size_t)(chb*4 + 2) * PLANE] = make_float4(a.z, c.z, d.z, e.z);
        *(float4*)&out[obase + (size_t)(chb*4 + 3) * PLANE] = make_float4(a.w, c.w, d.w, e.w);
    }
}

extern "C" void kernel_launch(void* const* d_in, const int* in_sizes, int n_in,
                              void* d_out, int out_size, void* d_ws, size_t ws_size,
                              hipStream_t stream) {
    const float* pos = (const float*)d_in[0];
    const float* scl = (const float*)d_in[1];
    const float* rot = (const float*)d_in[2];
    const float* opa = (const float*)d_in[3];
    const float* W1  = (const float*)d_in[4];
    const float* b1  = (const float*)d_in[5];
    const float* W2  = (const float*)d_in[6];
    const float* b2  = (const float*)d_in[7];
    const int*   vc  = (const int*)d_in[8];
    float* out = (float*)d_out;

    char* ws = (char*)d_ws;
    unsigned short* xwT = (unsigned short*)(ws);        // 2 MB: bf16 x^T [b][128][4096]
    float2* ml    = (float2*)(ws + (2u<<20));           // 256 KB
    float*  fused = (float*) (ws + (4u<<20));           // 16 MB
    int*    map   = (int*)   (ws + (20u<<20));          // 2 MB
    int*    vlist = (int*)   (ws + (22u<<20));          // 256 KB
    int*    cnt   = (int*)   (ws + (23u<<20));          // 8 B

    hipMemsetAsync(map, 0xFF, LOCS*sizeof(int), stream);
    hipMemsetAsync(cnt, 0, 2*sizeof(int), stream);
    hipMemsetAsync(fused, 0, (size_t)NV_*HID_*sizeof(float), stream);

    mlp_kernel<<<(B_*N_)/2, 256, 0, stream>>>(pos, scl, rot, opa, W1, b1, W2, b2, xwT);
    scatter_kernel<<<NV_/256, 256, 0, stream>>>(vc, map, cnt, vlist);
    ml_kernel<<<(NV_*8)/256, 256, 0, stream>>>(vc, ml);
    fuse_kernel<<<2*512*KS, 256, 0, stream>>>(xwT, ml, vc, vlist, cnt, fused);
    out_kernel<<<LOCS/(256*4), 256, 0, stream>>>(map, fused, out);
}